// Round 12
// baseline (352.754 us; speedup 1.0000x reference)
//
#include <hip/hip_runtime.h>
#include <hip/hip_cooperative_groups.h>

namespace cg = cooperative_groups;

#define NN 50000
#define NE 800000
#define NF 128
#define DIM 32
#define NG 500
#define BK 64                         // nodes per bucket
#define NB ((NN + BK - 1) / BK)       // 782 buckets
#define CB NB                         // cooperative blocks
#define CCHUNK ((NE + CB - 1) / CB)   // 1024 edges per block

__device__ __forceinline__ unsigned rne16(float f) {
    unsigned u = __float_as_uint(f);
    return (u + 0x7FFFu + ((u >> 16) & 1u)) >> 16;   // bf16 round-to-nearest-even
}

// ---------- k1: yp = bf16(x@w_rel) ; rootp = bf16(x@w_root + b_rel) ----------
__global__ __launch_bounds__(256) void proj_kernel(
    const float* __restrict__ x, const float* __restrict__ w_rel,
    const float* __restrict__ w_root, const float* __restrict__ b_rel,
    unsigned* __restrict__ yp, unsigned* __restrict__ rootp)
{
    __shared__ float s_w[2 * NF * DIM];   // 32 KB
    int tid = threadIdx.x;
    {
        const float4* wr4 = reinterpret_cast<const float4*>(w_rel);
        const float4* wo4 = reinterpret_cast<const float4*>(w_root);
        float4* s4 = reinterpret_cast<float4*>(s_w);
#pragma unroll
        for (int j = 0; j < 4; ++j) s4[tid + j * 256]        = wr4[tid + j * 256];
#pragma unroll
        for (int j = 0; j < 4; ++j) s4[1024 + tid + j * 256] = wo4[tid + j * 256];
    }

    int cg_ = tid & 15;
    int rg  = tid >> 4;
    int c0  = cg_ * 4;
    int rb  = blockIdx.x * 64 + rg * 4;

    const float* Wb = (c0 < DIM) ? (s_w + c0) : (s_w + NF * DIM + (c0 - DIM));

    int r0s = min(rb + 0, NN - 1);
    int r1s = min(rb + 1, NN - 1);
    int r2s = min(rb + 2, NN - 1);
    int r3s = min(rb + 3, NN - 1);
    const float* x0 = x + (size_t)r0s * NF;
    const float* x1 = x + (size_t)r1s * NF;
    const float* x2 = x + (size_t)r2s * NF;
    const float* x3 = x + (size_t)r3s * NF;

    __syncthreads();

    float4 a0 = {0,0,0,0}, a1 = {0,0,0,0}, a2 = {0,0,0,0}, a3 = {0,0,0,0};

#define F4FMA(acc, xv, wa, wb_, wc, wd)                                \
    acc.x = fmaf(xv.x, wa.x, acc.x);  acc.y = fmaf(xv.x, wa.y, acc.y); \
    acc.z = fmaf(xv.x, wa.z, acc.z);  acc.w = fmaf(xv.x, wa.w, acc.w); \
    acc.x = fmaf(xv.y, wb_.x, acc.x); acc.y = fmaf(xv.y, wb_.y, acc.y); \
    acc.z = fmaf(xv.y, wb_.z, acc.z); acc.w = fmaf(xv.y, wb_.w, acc.w); \
    acc.x = fmaf(xv.z, wc.x, acc.x);  acc.y = fmaf(xv.z, wc.y, acc.y); \
    acc.z = fmaf(xv.z, wc.z, acc.z);  acc.w = fmaf(xv.z, wc.w, acc.w); \
    acc.x = fmaf(xv.w, wd.x, acc.x);  acc.y = fmaf(xv.w, wd.y, acc.y); \
    acc.z = fmaf(xv.w, wd.z, acc.z);  acc.w = fmaf(xv.w, wd.w, acc.w)

    float4 na = *reinterpret_cast<const float4*>(x0);
    float4 nb = *reinterpret_cast<const float4*>(x1);
    float4 nc = *reinterpret_cast<const float4*>(x2);
    float4 nd = *reinterpret_cast<const float4*>(x3);
#pragma unroll
    for (int k = 0; k < NF; k += 4) {
        float4 xa = na, xb = nb, xc = nc, xd = nd;
        if (k + 4 < NF) {
            na = *reinterpret_cast<const float4*>(x0 + k + 4);
            nb = *reinterpret_cast<const float4*>(x1 + k + 4);
            nc = *reinterpret_cast<const float4*>(x2 + k + 4);
            nd = *reinterpret_cast<const float4*>(x3 + k + 4);
        }
        float4 wa  = *reinterpret_cast<const float4*>(Wb + (k + 0) * DIM);
        float4 wb2 = *reinterpret_cast<const float4*>(Wb + (k + 1) * DIM);
        float4 wc  = *reinterpret_cast<const float4*>(Wb + (k + 2) * DIM);
        float4 wd  = *reinterpret_cast<const float4*>(Wb + (k + 3) * DIM);
        F4FMA(a0, xa, wa, wb2, wc, wd);
        F4FMA(a1, xb, wa, wb2, wc, wd);
        F4FMA(a2, xc, wa, wb2, wc, wd);
        F4FMA(a3, xd, wa, wb2, wc, wd);
    }
#undef F4FMA

#define PACK2(v) make_uint2(rne16(v.x) | (rne16(v.y) << 16), rne16(v.z) | (rne16(v.w) << 16))
    if (c0 < DIM) {
        int cp0 = c0 >> 1;
        if (rb + 0 < NN) *reinterpret_cast<uint2*>(yp + (size_t)(rb+0) * 16 + cp0) = PACK2(a0);
        if (rb + 1 < NN) *reinterpret_cast<uint2*>(yp + (size_t)(rb+1) * 16 + cp0) = PACK2(a1);
        if (rb + 2 < NN) *reinterpret_cast<uint2*>(yp + (size_t)(rb+2) * 16 + cp0) = PACK2(a2);
        if (rb + 3 < NN) *reinterpret_cast<uint2*>(yp + (size_t)(rb+3) * 16 + cp0) = PACK2(a3);
    } else {
        int cc  = c0 - DIM;
        int cp0 = cc >> 1;
        float4 bi = *reinterpret_cast<const float4*>(b_rel + cc);
        a0.x += bi.x; a0.y += bi.y; a0.z += bi.z; a0.w += bi.w;
        a1.x += bi.x; a1.y += bi.y; a1.z += bi.z; a1.w += bi.w;
        a2.x += bi.x; a2.y += bi.y; a2.z += bi.z; a2.w += bi.w;
        a3.x += bi.x; a3.y += bi.y; a3.z += bi.z; a3.w += bi.w;
        if (rb + 0 < NN) *reinterpret_cast<uint2*>(rootp + (size_t)(rb+0) * 16 + cp0) = PACK2(a0);
        if (rb + 1 < NN) *reinterpret_cast<uint2*>(rootp + (size_t)(rb+1) * 16 + cp0) = PACK2(a1);
        if (rb + 2 < NN) *reinterpret_cast<uint2*>(rootp + (size_t)(rb+2) * 16 + cp0) = PACK2(a2);
        if (rb + 3 < NN) *reinterpret_cast<uint2*>(rootp + (size_t)(rb+3) * 16 + cp0) = PACK2(a3);
    }
#undef PACK2
}

// ---------- k2 (cooperative): hist -> colscan -> boff -> partition -> sort ----------
__global__ __launch_bounds__(256) void build_kernel(
    const int* __restrict__ ei, const float* __restrict__ ew,
    int* __restrict__ H, int* __restrict__ colsum,
    uint2* __restrict__ part, unsigned* __restrict__ csr,
    int* __restrict__ csr_off, float* __restrict__ pooled)
{
    cg::grid_group grid = cg::this_grid();
    __shared__ int sh[NB];          // hist, then cursors
    __shared__ int s_boff[NB + 1];
    __shared__ int s_scan[256];
    __shared__ int cnt[BK];
    __shared__ int cur2[BK];
    int blk = blockIdx.x, t = threadIdx.x;

    // ---- P0: zero pooled + per-block bucket histogram ----
    int pi = blk * 256 + t;
    if (pi < NG * DIM) pooled[pi] = 0.0f;
    for (int i = t; i < NB; i += 256) sh[i] = 0;
    __syncthreads();
    int base = blk * CCHUNK;
    int end  = min(base + CCHUNK, NE);
    for (int e = base + t; e < end; e += 256)
        atomicAdd(&sh[ei[NE + e] >> 6], 1);
    __syncthreads();
    for (int i = t; i < NB; i += 256) H[(size_t)blk * NB + i] = sh[i];
    grid.sync();

    // ---- P1: column prefix over block rows (one thread per bucket column) ----
    int col = blk * 256 + t;
    if (col < NB) {
        int run = 0;
        for (int r = 0; r < CB; ++r) {
            int v = H[(size_t)r * NB + col];
            H[(size_t)r * NB + col] = run;
            run += v;
        }
        colsum[col] = run;
    }
    grid.sync();

    // ---- P2: every block scans colsum -> s_boff (LDS, L2-hot 3 KB) ----
    {
        int v[4]; int sum = 0;
#pragma unroll
        for (int j = 0; j < 4; ++j) {
            int idx = t * 4 + j;
            v[j] = (idx < NB) ? colsum[idx] : 0;
            sum += v[j];
        }
        s_scan[t] = sum;
        __syncthreads();
        for (int o = 1; o < 256; o <<= 1) {
            int u = (t >= o) ? s_scan[t - o] : 0;
            __syncthreads();
            s_scan[t] += u;
            __syncthreads();
        }
        int b2 = s_scan[t] - sum;
#pragma unroll
        for (int j = 0; j < 4; ++j) {
            int idx = t * 4 + j;
            if (idx < NB) { s_boff[idx] = b2; b2 += v[j]; }
        }
        if (t == 0) s_boff[NB] = NE;
        __syncthreads();
    }
    // cursors: cur[i] = boff[i] + Hprefix[blk][i]
    for (int i = t; i < NB; i += 256) sh[i] = s_boff[i] + H[(size_t)blk * NB + i];
    __syncthreads();

    // ---- P3: partition this block's chunk (LDS cursors) ----
    for (int e = base + t; e < end; e += 256) {
        int s = ei[e], d = ei[NE + e];
        float w = ew[e];
        int b3 = d >> 6;
        int pos = atomicAdd(&sh[b3], 1);
        part[pos] = make_uint2((unsigned)s | ((unsigned)(d & 63) << 16),
                               __float_as_uint(w));
    }
    grid.sync();

    // ---- P4: per-bucket counting sort -> 4B CSR records ----
    if (t < BK) cnt[t] = 0;
    __syncthreads();
    int s0 = s_boff[blk], s1 = s_boff[blk + 1];
    for (int e = s0 + t; e < s1; e += 256)
        atomicAdd(&cnt[part[e].x >> 16], 1);
    __syncthreads();
    if (t < BK) {
        int v = cnt[t];
        int inc = v;
#pragma unroll
        for (int o = 1; o < BK; o <<= 1) {
            int u = __shfl_up(inc, o, 64);
            if (t >= o) inc += u;
        }
        int ex = inc - v;
        cur2[t] = ex;
        csr_off[blk * BK + t] = s0 + ex;
    }
    if (blk == CB - 1 && t == 0) csr_off[NB * BK] = NE;
    __syncthreads();
    for (int e = s0 + t; e < s1; e += 256) {
        uint2 pk = part[e];
        int nl = pk.x >> 16;
        int pos = atomicAdd(&cur2[nl], 1);
        csr[s0 + pos] = (pk.x & 0xFFFFu) | (rne16(__uint_as_float(pk.y)) << 16);
    }
}

// ---------- k3: wave64/node, 8 edge slots x 8 lanes (uint2 y loads) ----------
#define UIF __uint_as_float
__device__ __forceinline__ float blo(unsigned p) { return UIF(p << 16); }
__device__ __forceinline__ float bhi(unsigned p) { return UIF(p & 0xFFFF0000u); }

__global__ __launch_bounds__(256) void nodeagg_kernel(
    const uint2* __restrict__ ypq, const uint2* __restrict__ rootq,
    const int* __restrict__ csr_off, const unsigned* __restrict__ csr,
    const int* __restrict__ batch, float* __restrict__ pooled)
{
    __shared__ float s_p[4][DIM];
    __shared__ int   s_g[4];
    int t    = threadIdx.x;
    int w    = t >> 6;                    // wave id 0..3
    int lane = t & 63;
    int s    = lane >> 3;                 // edge slot 0..7
    int j    = lane & 7;                  // col quad -> cols 4j..4j+3
    int n    = blockIdx.x * 4 + w;        // NN % 4 == 0

    float v0 = 0.0f, v1 = 0.0f, v2 = 0.0f, v3 = 0.0f;
    int e1 = csr_off[n + 1];
    int e  = csr_off[n] + s;
    for (; e + 8 < e1; e += 16) {         // 16 edges per round (2 per slot)
        unsigned c0 = csr[e], c1 = csr[e + 8];
        uint2 p0 = ypq[(c0 & 0xFFFFu) * 8 + j];
        uint2 p1 = ypq[(c1 & 0xFFFFu) * 8 + j];
        float w0 = UIF(c0 & 0xFFFF0000u), w1 = UIF(c1 & 0xFFFF0000u);
        v0 = fmaf(w0, blo(p0.x), v0); v1 = fmaf(w0, bhi(p0.x), v1);
        v2 = fmaf(w0, blo(p0.y), v2); v3 = fmaf(w0, bhi(p0.y), v3);
        v0 = fmaf(w1, blo(p1.x), v0); v1 = fmaf(w1, bhi(p1.x), v1);
        v2 = fmaf(w1, blo(p1.y), v2); v3 = fmaf(w1, bhi(p1.y), v3);
    }
    for (; e < e1; e += 8) {
        unsigned cu = csr[e];
        uint2 p = ypq[(cu & 0xFFFFu) * 8 + j];
        float ww = UIF(cu & 0xFFFF0000u);
        v0 = fmaf(ww, blo(p.x), v0); v1 = fmaf(ww, bhi(p.x), v1);
        v2 = fmaf(ww, blo(p.y), v2); v3 = fmaf(ww, bhi(p.y), v3);
    }
    // combine the 8 edge slots (strides 8,16,32)
    v0 += __shfl_xor(v0, 8, 64); v0 += __shfl_xor(v0, 16, 64); v0 += __shfl_xor(v0, 32, 64);
    v1 += __shfl_xor(v1, 8, 64); v1 += __shfl_xor(v1, 16, 64); v1 += __shfl_xor(v1, 32, 64);
    v2 += __shfl_xor(v2, 8, 64); v2 += __shfl_xor(v2, 16, 64); v2 += __shfl_xor(v2, 32, 64);
    v3 += __shfl_xor(v3, 8, 64); v3 += __shfl_xor(v3, 16, 64); v3 += __shfl_xor(v3, 32, 64);

    if (s == 0) {                          // lanes 0..7 finalize 4 cols each
        uint2 r = rootq[(size_t)n * 8 + j];
        float4 o;
        o.x = fmaxf(v0 + blo(r.x), 0.0f);
        o.y = fmaxf(v1 + bhi(r.x), 0.0f);
        o.z = fmaxf(v2 + blo(r.y), 0.0f);
        o.w = fmaxf(v3 + bhi(r.y), 0.0f);
        *reinterpret_cast<float4*>(&s_p[w][4 * j]) = o;
        if (j == 0) s_g[w] = batch[n];
    }
    __syncthreads();
    if (t < DIM) {
        int curg = s_g[0];
        float run = s_p[0][t];
#pragma unroll
        for (int jj = 1; jj < 4; ++jj) {
            int g = s_g[jj];
            float v = s_p[jj][t];
            if (g != curg) {
                atomicAdd(&pooled[curg * DIM + t], run);
                curg = g; run = v;
            } else run += v;
        }
        atomicAdd(&pooled[curg * DIM + t], run);
    }
}

// ---------- k4: MLP head + log_softmax ----------
__global__ __launch_bounds__(512) void head_kernel(
    const float* __restrict__ pooled, const float* __restrict__ w_fc1,
    const float* __restrict__ b_fc1, const float* __restrict__ w_fc2,
    const float* __restrict__ b_fc2, float* __restrict__ out)
{
    __shared__ float s_fc1[DIM * DIM];
    __shared__ float s_b1[DIM];
    __shared__ float s_fc2[DIM * 2];
    __shared__ float s_b2[2];
    int tid = threadIdx.x;
    s_fc1[tid]       = w_fc1[tid];
    s_fc1[tid + 512] = w_fc1[tid + 512];
    if (tid < DIM * 2) s_fc2[tid] = w_fc2[tid];
    if (tid < DIM)     s_b1[tid]  = b_fc1[tid];
    if (tid < 2)       s_b2[tid]  = b_fc2[tid];
    __syncthreads();

    int g = tid;
    if (g >= NG) return;
    const float* p = pooled + g * DIM;
    float h2[DIM];
#pragma unroll
    for (int c = 0; c < DIM; ++c) {
        float a = s_b1[c];
#pragma unroll
        for (int k = 0; k < DIM; ++k)
            a = fmaf(p[k], s_fc1[k * DIM + c], a);
        h2[c] = a > 0.0f ? a : 0.0f;
    }
    float l0 = s_b2[0], l1 = s_b2[1];
#pragma unroll
    for (int c = 0; c < DIM; ++c) {
        l0 = fmaf(h2[c], s_fc2[c * 2 + 0], l0);
        l1 = fmaf(h2[c], s_fc2[c * 2 + 1], l1);
    }
    float m   = fmaxf(l0, l1);
    float lse = m + logf(expf(l0 - m) + expf(l1 - m));
    out[g * 2 + 0] = l0 - lse;
    out[g * 2 + 1] = l1 - lse;
}

extern "C" void kernel_launch(void* const* d_in, const int* in_sizes, int n_in,
                              void* d_out, int out_size, void* d_ws, size_t ws_size,
                              hipStream_t stream) {
    const float* x      = (const float*)d_in[0];
    const float* ew     = (const float*)d_in[1];
    const float* w_rel  = (const float*)d_in[2];
    const float* b_rel  = (const float*)d_in[3];
    const float* w_root = (const float*)d_in[4];
    const float* w_fc1  = (const float*)d_in[5];
    const float* b_fc1  = (const float*)d_in[6];
    const float* w_fc2  = (const float*)d_in[7];
    const float* b_fc2  = (const float*)d_in[8];
    const int*   ei     = (const int*)d_in[9];
    const int*   batch  = (const int*)d_in[10];
    float* out = (float*)d_out;

    char* ws = (char*)d_ws;
    unsigned* yp    = (unsigned*)ws;                           // 3.2 MB (bf16x2)
    unsigned* rootp = yp + (size_t)NN * 16;                    // 3.2 MB (bf16x2)
    uint2* part     = (uint2*)(rootp + (size_t)NN * 16);       // 6.4 MB
    unsigned* csr   = (unsigned*)(part + NE);                  // 3.2 MB (4B records)
    int*   H        = (int*)(csr + NE);                        // CB*NB = 2.45 MB
    int*   colsum   = H + (size_t)CB * NB;                     // NB
    int*   csr_off  = colsum + NB;                             // NB*BK+1
    float* pooled   = (float*)(csr_off + NB * BK + 2);         // 64 KB

    proj_kernel<<<NB, 256, 0, stream>>>(x, w_rel, w_root, b_rel, yp, rootp);

    {
        void* ei_p = (void*)ei;   void* ew_p = (void*)ew;
        void* H_p = (void*)H;     void* cs_p = (void*)colsum;
        void* pa_p = (void*)part; void* cr_p = (void*)csr;
        void* co_p = (void*)csr_off; void* po_p = (void*)pooled;
        void* args[] = { &ei_p, &ew_p, &H_p, &cs_p, &pa_p, &cr_p, &co_p, &po_p };
        hipLaunchCooperativeKernel((const void*)build_kernel,
                                   dim3(CB), dim3(256), args, 0, stream);
    }

    nodeagg_kernel<<<NN / 4, 256, 0, stream>>>((const uint2*)yp, (const uint2*)rootp,
                                               csr_off, csr, batch, pooled);
    head_kernel<<<1, 512, 0, stream>>>(pooled, w_fc1, b_fc1, w_fc2, b_fc2, out);
}

// Round 13
// 97.676 us; speedup vs baseline: 3.6115x; 3.6115x over previous
//
#include <hip/hip_runtime.h>

#define NN 50000
#define NE 800000
#define NF 128
#define DIM 32
#define NG 500
#define BK 64                         // nodes per bucket
#define NB ((NN + BK - 1) / BK)       // 782 buckets
#define HB 256                        // histogram/partition blocks
#define CHUNK_E ((NE + HB - 1) / HB)  // 3125 edges per block

__device__ __forceinline__ unsigned rne16(float f) {
    unsigned u = __float_as_uint(f);
    return (u + 0x7FFFu + ((u >> 16) & 1u)) >> 16;   // bf16 round-to-nearest-even
}

// ---------- k1: yp = bf16(x@w_rel) ; rootp = bf16(x@w_root + b_rel) ----------
__global__ __launch_bounds__(256) void proj_kernel(
    const float* __restrict__ x, const float* __restrict__ w_rel,
    const float* __restrict__ w_root, const float* __restrict__ b_rel,
    unsigned* __restrict__ yp, unsigned* __restrict__ rootp)
{
    __shared__ float s_w[2 * NF * DIM];   // 32 KB
    int tid = threadIdx.x;
    {
        const float4* wr4 = reinterpret_cast<const float4*>(w_rel);
        const float4* wo4 = reinterpret_cast<const float4*>(w_root);
        float4* s4 = reinterpret_cast<float4*>(s_w);
#pragma unroll
        for (int j = 0; j < 4; ++j) s4[tid + j * 256]        = wr4[tid + j * 256];
#pragma unroll
        for (int j = 0; j < 4; ++j) s4[1024 + tid + j * 256] = wo4[tid + j * 256];
    }

    int cg_ = tid & 15;
    int rg  = tid >> 4;
    int c0  = cg_ * 4;
    int rb  = blockIdx.x * 64 + rg * 4;

    const float* Wb = (c0 < DIM) ? (s_w + c0) : (s_w + NF * DIM + (c0 - DIM));

    int r0s = min(rb + 0, NN - 1);
    int r1s = min(rb + 1, NN - 1);
    int r2s = min(rb + 2, NN - 1);
    int r3s = min(rb + 3, NN - 1);
    const float* x0 = x + (size_t)r0s * NF;
    const float* x1 = x + (size_t)r1s * NF;
    const float* x2 = x + (size_t)r2s * NF;
    const float* x3 = x + (size_t)r3s * NF;

    __syncthreads();

    float4 a0 = {0,0,0,0}, a1 = {0,0,0,0}, a2 = {0,0,0,0}, a3 = {0,0,0,0};

#define F4FMA(acc, xv, wa, wb_, wc, wd)                                \
    acc.x = fmaf(xv.x, wa.x, acc.x);  acc.y = fmaf(xv.x, wa.y, acc.y); \
    acc.z = fmaf(xv.x, wa.z, acc.z);  acc.w = fmaf(xv.x, wa.w, acc.w); \
    acc.x = fmaf(xv.y, wb_.x, acc.x); acc.y = fmaf(xv.y, wb_.y, acc.y); \
    acc.z = fmaf(xv.y, wb_.z, acc.z); acc.w = fmaf(xv.y, wb_.w, acc.w); \
    acc.x = fmaf(xv.z, wc.x, acc.x);  acc.y = fmaf(xv.z, wc.y, acc.y); \
    acc.z = fmaf(xv.z, wc.z, acc.z);  acc.w = fmaf(xv.z, wc.w, acc.w); \
    acc.x = fmaf(xv.w, wd.x, acc.x);  acc.y = fmaf(xv.w, wd.y, acc.y); \
    acc.z = fmaf(xv.w, wd.z, acc.z);  acc.w = fmaf(xv.w, wd.w, acc.w)

    float4 na = *reinterpret_cast<const float4*>(x0);
    float4 nb = *reinterpret_cast<const float4*>(x1);
    float4 nc = *reinterpret_cast<const float4*>(x2);
    float4 nd = *reinterpret_cast<const float4*>(x3);
#pragma unroll
    for (int k = 0; k < NF; k += 4) {
        float4 xa = na, xb = nb, xc = nc, xd = nd;
        if (k + 4 < NF) {
            na = *reinterpret_cast<const float4*>(x0 + k + 4);
            nb = *reinterpret_cast<const float4*>(x1 + k + 4);
            nc = *reinterpret_cast<const float4*>(x2 + k + 4);
            nd = *reinterpret_cast<const float4*>(x3 + k + 4);
        }
        float4 wa  = *reinterpret_cast<const float4*>(Wb + (k + 0) * DIM);
        float4 wb2 = *reinterpret_cast<const float4*>(Wb + (k + 1) * DIM);
        float4 wc  = *reinterpret_cast<const float4*>(Wb + (k + 2) * DIM);
        float4 wd  = *reinterpret_cast<const float4*>(Wb + (k + 3) * DIM);
        F4FMA(a0, xa, wa, wb2, wc, wd);
        F4FMA(a1, xb, wa, wb2, wc, wd);
        F4FMA(a2, xc, wa, wb2, wc, wd);
        F4FMA(a3, xd, wa, wb2, wc, wd);
    }
#undef F4FMA

#define PACK2(v) make_uint2(rne16(v.x) | (rne16(v.y) << 16), rne16(v.z) | (rne16(v.w) << 16))
    if (c0 < DIM) {
        int cp0 = c0 >> 1;
        if (rb + 0 < NN) *reinterpret_cast<uint2*>(yp + (size_t)(rb+0) * 16 + cp0) = PACK2(a0);
        if (rb + 1 < NN) *reinterpret_cast<uint2*>(yp + (size_t)(rb+1) * 16 + cp0) = PACK2(a1);
        if (rb + 2 < NN) *reinterpret_cast<uint2*>(yp + (size_t)(rb+2) * 16 + cp0) = PACK2(a2);
        if (rb + 3 < NN) *reinterpret_cast<uint2*>(yp + (size_t)(rb+3) * 16 + cp0) = PACK2(a3);
    } else {
        int cc  = c0 - DIM;
        int cp0 = cc >> 1;
        float4 bi = *reinterpret_cast<const float4*>(b_rel + cc);
        a0.x += bi.x; a0.y += bi.y; a0.z += bi.z; a0.w += bi.w;
        a1.x += bi.x; a1.y += bi.y; a1.z += bi.z; a1.w += bi.w;
        a2.x += bi.x; a2.y += bi.y; a2.z += bi.z; a2.w += bi.w;
        a3.x += bi.x; a3.y += bi.y; a3.z += bi.z; a3.w += bi.w;
        if (rb + 0 < NN) *reinterpret_cast<uint2*>(rootp + (size_t)(rb+0) * 16 + cp0) = PACK2(a0);
        if (rb + 1 < NN) *reinterpret_cast<uint2*>(rootp + (size_t)(rb+1) * 16 + cp0) = PACK2(a1);
        if (rb + 2 < NN) *reinterpret_cast<uint2*>(rootp + (size_t)(rb+2) * 16 + cp0) = PACK2(a2);
        if (rb + 3 < NN) *reinterpret_cast<uint2*>(rootp + (size_t)(rb+3) * 16 + cp0) = PACK2(a3);
    }
#undef PACK2
}

// ---------- k2: per-block bucket histogram (LDS) + zero pooled ----------
__global__ __launch_bounds__(256) void histk(
    const int* __restrict__ ei, int* __restrict__ H, float* __restrict__ pooled)
{
    int pi = blockIdx.x * 256 + threadIdx.x;
    if (pi < NG * DIM) pooled[pi] = 0.0f;

    __shared__ int sh[NB];
    int t = threadIdx.x;
    for (int i = t; i < NB; i += 256) sh[i] = 0;
    __syncthreads();
    int base = blockIdx.x * CHUNK_E;
    int end  = min(base + CHUNK_E, NE);
    for (int e = base + t; e < end; e += 256)
        atomicAdd(&sh[ei[NE + e] >> 6], 1);
    __syncthreads();
    for (int i = t; i < NB; i += 256) H[blockIdx.x * NB + i] = sh[i];
}

// ---------- k3: column prefix over the HB block rows -> colsum ----------
__global__ __launch_bounds__(256) void colscan(
    int* __restrict__ H, int* __restrict__ colsum)
{
    int b = blockIdx.x * 256 + threadIdx.x;
    if (b >= NB) return;
    int run = 0;
#pragma unroll 8
    for (int blk = 0; blk < HB; ++blk) {
        int v = H[blk * NB + b];   // coalesced across threads
        H[blk * NB + b] = run;
        run += v;
    }
    colsum[b] = run;
}

// shared helper: 256-thread LDS exclusive scan of colsum -> s_boff[NB+1]
__device__ __forceinline__ void scan_colsum(
    const int* __restrict__ colsum, int* s_scan, int* s_boff, int t)
{
    int v[4]; int sum = 0;
#pragma unroll
    for (int j = 0; j < 4; ++j) {
        int idx = t * 4 + j;
        v[j] = (idx < NB) ? colsum[idx] : 0;
        sum += v[j];
    }
    s_scan[t] = sum;
    __syncthreads();
    for (int o = 1; o < 256; o <<= 1) {
        int u = (t >= o) ? s_scan[t - o] : 0;
        __syncthreads();
        s_scan[t] += u;
        __syncthreads();
    }
    int b2 = s_scan[t] - sum;
#pragma unroll
    for (int j = 0; j < 4; ++j) {
        int idx = t * 4 + j;
        if (idx < NB) { s_boff[idx] = b2; b2 += v[j]; }
    }
    if (t == 0) s_boff[NB] = NE;
    __syncthreads();
}

// ---------- k4: partition (LDS-scans colsum itself; no bscan2 dispatch) ----------
__global__ __launch_bounds__(256) void partition_kernel(
    const int* __restrict__ ei, const float* __restrict__ ew,
    const int* __restrict__ H, const int* __restrict__ colsum,
    uint2* __restrict__ part)
{
    __shared__ int s_scan[256];
    __shared__ int s_boff[NB + 1];
    __shared__ int cur[NB];
    int t = threadIdx.x;
    scan_colsum(colsum, s_scan, s_boff, t);
    for (int i = t; i < NB; i += 256)
        cur[i] = s_boff[i] + H[blockIdx.x * NB + i];
    __syncthreads();
    int base = blockIdx.x * CHUNK_E;
    int end  = min(base + CHUNK_E, NE);
    for (int e = base + t; e < end; e += 256) {
        int s = ei[e], d = ei[NE + e];
        float w = ew[e];
        int b = d >> 6;
        int pos = atomicAdd(&cur[b], 1);   // LDS atomic, block-local
        part[pos] = make_uint2((unsigned)s | ((unsigned)(d & 63) << 16),
                               __float_as_uint(w));
    }
}

// ---------- k5: per-bucket counting sort -> 4B CSR (LDS-scans colsum) ----------
__global__ __launch_bounds__(256) void bucketsort_kernel(
    const uint2* __restrict__ part, const int* __restrict__ colsum,
    unsigned* __restrict__ csr, int* __restrict__ csr_off)
{
    __shared__ int s_scan[256];
    __shared__ int s_boff[NB + 1];
    __shared__ int cnt[BK];
    __shared__ int cur[BK];
    int b = blockIdx.x, t = threadIdx.x;
    scan_colsum(colsum, s_scan, s_boff, t);
    if (t < BK) cnt[t] = 0;
    __syncthreads();
    int s0 = s_boff[b], s1 = s_boff[b + 1];
    for (int e = s0 + t; e < s1; e += 256)
        atomicAdd(&cnt[part[e].x >> 16], 1);
    __syncthreads();
    if (t < BK) {
        int v = cnt[t];
        int inc = v;
#pragma unroll
        for (int o = 1; o < BK; o <<= 1) {
            int u = __shfl_up(inc, o, 64);
            if (t >= o) inc += u;
        }
        int ex = inc - v;
        cur[t] = ex;
        csr_off[b * BK + t] = s0 + ex;
    }
    if (b == NB - 1 && t == 0) csr_off[NB * BK] = NE;
    __syncthreads();
    for (int e = s0 + t; e < s1; e += 256) {
        uint2 pk = part[e];
        int nl = pk.x >> 16;
        int pos = atomicAdd(&cur[nl], 1);
        csr[s0 + pos] = (pk.x & 0xFFFFu) | (rne16(__uint_as_float(pk.y)) << 16);
    }
}

// ---------- k6: wave64/node, 8 edge slots x 8 lanes (uint2 y loads) ----------
#define UIF __uint_as_float
__device__ __forceinline__ float blo(unsigned p) { return UIF(p << 16); }
__device__ __forceinline__ float bhi(unsigned p) { return UIF(p & 0xFFFF0000u); }

__global__ __launch_bounds__(256) void nodeagg_kernel(
    const uint2* __restrict__ ypq, const uint2* __restrict__ rootq,
    const int* __restrict__ csr_off, const unsigned* __restrict__ csr,
    const int* __restrict__ batch, float* __restrict__ pooled)
{
    __shared__ float s_p[4][DIM];
    __shared__ int   s_g[4];
    int t    = threadIdx.x;
    int w    = t >> 6;                    // wave id 0..3
    int lane = t & 63;
    int s    = lane >> 3;                 // edge slot 0..7
    int j    = lane & 7;                  // col quad -> cols 4j..4j+3
    int n    = blockIdx.x * 4 + w;        // NN % 4 == 0

    float v0 = 0.0f, v1 = 0.0f, v2 = 0.0f, v3 = 0.0f;
    int e1 = csr_off[n + 1];
    int e  = csr_off[n] + s;
    for (; e + 8 < e1; e += 16) {         // 16 edges per round (2 per slot)
        unsigned c0 = csr[e], c1 = csr[e + 8];
        uint2 p0 = ypq[(c0 & 0xFFFFu) * 8 + j];
        uint2 p1 = ypq[(c1 & 0xFFFFu) * 8 + j];
        float w0 = UIF(c0 & 0xFFFF0000u), w1 = UIF(c1 & 0xFFFF0000u);
        v0 = fmaf(w0, blo(p0.x), v0); v1 = fmaf(w0, bhi(p0.x), v1);
        v2 = fmaf(w0, blo(p0.y), v2); v3 = fmaf(w0, bhi(p0.y), v3);
        v0 = fmaf(w1, blo(p1.x), v0); v1 = fmaf(w1, bhi(p1.x), v1);
        v2 = fmaf(w1, blo(p1.y), v2); v3 = fmaf(w1, bhi(p1.y), v3);
    }
    for (; e < e1; e += 8) {
        unsigned cu = csr[e];
        uint2 p = ypq[(cu & 0xFFFFu) * 8 + j];
        float ww = UIF(cu & 0xFFFF0000u);
        v0 = fmaf(ww, blo(p.x), v0); v1 = fmaf(ww, bhi(p.x), v1);
        v2 = fmaf(ww, blo(p.y), v2); v3 = fmaf(ww, bhi(p.y), v3);
    }
    v0 += __shfl_xor(v0, 8, 64); v0 += __shfl_xor(v0, 16, 64); v0 += __shfl_xor(v0, 32, 64);
    v1 += __shfl_xor(v1, 8, 64); v1 += __shfl_xor(v1, 16, 64); v1 += __shfl_xor(v1, 32, 64);
    v2 += __shfl_xor(v2, 8, 64); v2 += __shfl_xor(v2, 16, 64); v2 += __shfl_xor(v2, 32, 64);
    v3 += __shfl_xor(v3, 8, 64); v3 += __shfl_xor(v3, 16, 64); v3 += __shfl_xor(v3, 32, 64);

    if (s == 0) {                          // lanes 0..7 finalize 4 cols each
        uint2 r = rootq[(size_t)n * 8 + j];
        float4 o;
        o.x = fmaxf(v0 + blo(r.x), 0.0f);
        o.y = fmaxf(v1 + bhi(r.x), 0.0f);
        o.z = fmaxf(v2 + blo(r.y), 0.0f);
        o.w = fmaxf(v3 + bhi(r.y), 0.0f);
        *reinterpret_cast<float4*>(&s_p[w][4 * j]) = o;
        if (j == 0) s_g[w] = batch[n];
    }
    __syncthreads();
    if (t < DIM) {
        int curg = s_g[0];
        float run = s_p[0][t];
#pragma unroll
        for (int jj = 1; jj < 4; ++jj) {
            int g = s_g[jj];
            float v = s_p[jj][t];
            if (g != curg) {
                atomicAdd(&pooled[curg * DIM + t], run);
                curg = g; run = v;
            } else run += v;
        }
        atomicAdd(&pooled[curg * DIM + t], run);
    }
}

// ---------- k7: MLP head + log_softmax ----------
__global__ __launch_bounds__(512) void head_kernel(
    const float* __restrict__ pooled, const float* __restrict__ w_fc1,
    const float* __restrict__ b_fc1, const float* __restrict__ w_fc2,
    const float* __restrict__ b_fc2, float* __restrict__ out)
{
    __shared__ float s_fc1[DIM * DIM];
    __shared__ float s_b1[DIM];
    __shared__ float s_fc2[DIM * 2];
    __shared__ float s_b2[2];
    int tid = threadIdx.x;
    s_fc1[tid]       = w_fc1[tid];
    s_fc1[tid + 512] = w_fc1[tid + 512];
    if (tid < DIM * 2) s_fc2[tid] = w_fc2[tid];
    if (tid < DIM)     s_b1[tid]  = b_fc1[tid];
    if (tid < 2)       s_b2[tid]  = b_fc2[tid];
    __syncthreads();

    int g = tid;
    if (g >= NG) return;
    const float* p = pooled + g * DIM;
    float h2[DIM];
#pragma unroll
    for (int c = 0; c < DIM; ++c) {
        float a = s_b1[c];
#pragma unroll
        for (int k = 0; k < DIM; ++k)
            a = fmaf(p[k], s_fc1[k * DIM + c], a);
        h2[c] = a > 0.0f ? a : 0.0f;
    }
    float l0 = s_b2[0], l1 = s_b2[1];
#pragma unroll
    for (int c = 0; c < DIM; ++c) {
        l0 = fmaf(h2[c], s_fc2[c * 2 + 0], l0);
        l1 = fmaf(h2[c], s_fc2[c * 2 + 1], l1);
    }
    float m   = fmaxf(l0, l1);
    float lse = m + logf(expf(l0 - m) + expf(l1 - m));
    out[g * 2 + 0] = l0 - lse;
    out[g * 2 + 1] = l1 - lse;
}

extern "C" void kernel_launch(void* const* d_in, const int* in_sizes, int n_in,
                              void* d_out, int out_size, void* d_ws, size_t ws_size,
                              hipStream_t stream) {
    const float* x      = (const float*)d_in[0];
    const float* ew     = (const float*)d_in[1];
    const float* w_rel  = (const float*)d_in[2];
    const float* b_rel  = (const float*)d_in[3];
    const float* w_root = (const float*)d_in[4];
    const float* w_fc1  = (const float*)d_in[5];
    const float* b_fc1  = (const float*)d_in[6];
    const float* w_fc2  = (const float*)d_in[7];
    const float* b_fc2  = (const float*)d_in[8];
    const int*   ei     = (const int*)d_in[9];
    const int*   batch  = (const int*)d_in[10];
    float* out = (float*)d_out;

    char* ws = (char*)d_ws;
    unsigned* yp    = (unsigned*)ws;                           // 3.2 MB (bf16x2)
    unsigned* rootp = yp + (size_t)NN * 16;                    // 3.2 MB (bf16x2)
    uint2* part     = (uint2*)(rootp + (size_t)NN * 16);       // 6.4 MB
    unsigned* csr   = (unsigned*)(part + NE);                  // 3.2 MB (4B records)
    int*   H        = (int*)(csr + NE);                        // HB*NB = 800 KB
    int*   colsum   = H + (size_t)HB * NB;                     // NB
    int*   csr_off  = colsum + NB;                             // NB*BK+1
    float* pooled   = (float*)(csr_off + NB * BK + 2);         // 64 KB

    proj_kernel<<<NB, 256, 0, stream>>>(x, w_rel, w_root, b_rel, yp, rootp);
    histk<<<HB, 256, 0, stream>>>(ei, H, pooled);
    colscan<<<(NB + 255) / 256, 256, 0, stream>>>(H, colsum);
    partition_kernel<<<HB, 256, 0, stream>>>(ei, ew, H, colsum, part);
    bucketsort_kernel<<<NB, 256, 0, stream>>>(part, colsum, csr, csr_off);
    nodeagg_kernel<<<NN / 4, 256, 0, stream>>>((const uint2*)yp, (const uint2*)rootp,
                                               csr_off, csr, batch, pooled);
    head_kernel<<<1, 512, 0, stream>>>(pooled, w_fc1, b_fc1, w_fc2, b_fc2, out);
}

// Round 14
// 88.026 us; speedup vs baseline: 4.0074x; 1.1096x over previous
//
#include <hip/hip_runtime.h>

#define NN 50000
#define NE 800000
#define NF 128
#define DIM 32
#define NG 500
#define BK 64                         // nodes per bucket
#define NB ((NN + BK - 1) / BK)       // 782 buckets
#define HB 256                        // histogram/partition blocks
#define CHUNK_E ((NE + HB - 1) / HB)  // 3125 edges per block
#define CAP 2048                      // LDS csr capacity (mean 1024, sigma 32)

__device__ __forceinline__ unsigned rne16(float f) {
    unsigned u = __float_as_uint(f);
    return (u + 0x7FFFu + ((u >> 16) & 1u)) >> 16;   // bf16 round-to-nearest-even
}
#define UIF __uint_as_float
__device__ __forceinline__ float blo(unsigned p) { return UIF(p << 16); }
__device__ __forceinline__ float bhi(unsigned p) { return UIF(p & 0xFFFF0000u); }

// ---------- k1: [blocks 0..NB-1] proj ; [blocks NB..NB+HB-1] histk + zero pooled ----------
__global__ __launch_bounds__(256) void projhist_kernel(
    const float* __restrict__ x, const float* __restrict__ w_rel,
    const float* __restrict__ w_root, const float* __restrict__ b_rel,
    unsigned* __restrict__ yp, unsigned* __restrict__ rootp,
    const int* __restrict__ ei, int* __restrict__ H, float* __restrict__ pooled)
{
    __shared__ float s_w[2 * NF * DIM];   // 32 KB (histk branch reuses as int[])
    int tid = threadIdx.x;

    if (blockIdx.x >= NB) {
        // ---- histk branch ----
        int blk = blockIdx.x - NB;
        int* sh = (int*)s_w;
        int pi = blk * 256 + tid;
        if (pi < NG * DIM) pooled[pi] = 0.0f;
        for (int i = tid; i < NB; i += 256) sh[i] = 0;
        __syncthreads();
        int base = blk * CHUNK_E;
        int end  = min(base + CHUNK_E, NE);
        for (int e = base + tid; e < end; e += 256)
            atomicAdd(&sh[ei[NE + e] >> 6], 1);
        __syncthreads();
        for (int i = tid; i < NB; i += 256) H[blk * NB + i] = sh[i];
        return;
    }

    // ---- proj branch ----
    {
        const float4* wr4 = reinterpret_cast<const float4*>(w_rel);
        const float4* wo4 = reinterpret_cast<const float4*>(w_root);
        float4* s4 = reinterpret_cast<float4*>(s_w);
#pragma unroll
        for (int j = 0; j < 4; ++j) s4[tid + j * 256]        = wr4[tid + j * 256];
#pragma unroll
        for (int j = 0; j < 4; ++j) s4[1024 + tid + j * 256] = wo4[tid + j * 256];
    }

    int cg_ = tid & 15;
    int rg  = tid >> 4;
    int c0  = cg_ * 4;
    int rb  = blockIdx.x * 64 + rg * 4;

    const float* Wb = (c0 < DIM) ? (s_w + c0) : (s_w + NF * DIM + (c0 - DIM));

    int r0s = min(rb + 0, NN - 1);
    int r1s = min(rb + 1, NN - 1);
    int r2s = min(rb + 2, NN - 1);
    int r3s = min(rb + 3, NN - 1);
    const float* x0 = x + (size_t)r0s * NF;
    const float* x1 = x + (size_t)r1s * NF;
    const float* x2 = x + (size_t)r2s * NF;
    const float* x3 = x + (size_t)r3s * NF;

    __syncthreads();

    float4 a0 = {0,0,0,0}, a1 = {0,0,0,0}, a2 = {0,0,0,0}, a3 = {0,0,0,0};

#define F4FMA(acc, xv, wa, wb_, wc, wd)                                \
    acc.x = fmaf(xv.x, wa.x, acc.x);  acc.y = fmaf(xv.x, wa.y, acc.y); \
    acc.z = fmaf(xv.x, wa.z, acc.z);  acc.w = fmaf(xv.x, wa.w, acc.w); \
    acc.x = fmaf(xv.y, wb_.x, acc.x); acc.y = fmaf(xv.y, wb_.y, acc.y); \
    acc.z = fmaf(xv.y, wb_.z, acc.z); acc.w = fmaf(xv.y, wb_.w, acc.w); \
    acc.x = fmaf(xv.z, wc.x, acc.x);  acc.y = fmaf(xv.z, wc.y, acc.y); \
    acc.z = fmaf(xv.z, wc.z, acc.z);  acc.w = fmaf(xv.z, wc.w, acc.w); \
    acc.x = fmaf(xv.w, wd.x, acc.x);  acc.y = fmaf(xv.w, wd.y, acc.y); \
    acc.z = fmaf(xv.w, wd.z, acc.z);  acc.w = fmaf(xv.w, wd.w, acc.w)

    float4 na = *reinterpret_cast<const float4*>(x0);
    float4 nb = *reinterpret_cast<const float4*>(x1);
    float4 nc = *reinterpret_cast<const float4*>(x2);
    float4 nd = *reinterpret_cast<const float4*>(x3);
#pragma unroll
    for (int k = 0; k < NF; k += 4) {
        float4 xa = na, xb = nb, xc = nc, xd = nd;
        if (k + 4 < NF) {
            na = *reinterpret_cast<const float4*>(x0 + k + 4);
            nb = *reinterpret_cast<const float4*>(x1 + k + 4);
            nc = *reinterpret_cast<const float4*>(x2 + k + 4);
            nd = *reinterpret_cast<const float4*>(x3 + k + 4);
        }
        float4 wa  = *reinterpret_cast<const float4*>(Wb + (k + 0) * DIM);
        float4 wb2 = *reinterpret_cast<const float4*>(Wb + (k + 1) * DIM);
        float4 wc  = *reinterpret_cast<const float4*>(Wb + (k + 2) * DIM);
        float4 wd  = *reinterpret_cast<const float4*>(Wb + (k + 3) * DIM);
        F4FMA(a0, xa, wa, wb2, wc, wd);
        F4FMA(a1, xb, wa, wb2, wc, wd);
        F4FMA(a2, xc, wa, wb2, wc, wd);
        F4FMA(a3, xd, wa, wb2, wc, wd);
    }
#undef F4FMA

#define PACK2(v) make_uint2(rne16(v.x) | (rne16(v.y) << 16), rne16(v.z) | (rne16(v.w) << 16))
    if (c0 < DIM) {
        int cp0 = c0 >> 1;
        if (rb + 0 < NN) *reinterpret_cast<uint2*>(yp + (size_t)(rb+0) * 16 + cp0) = PACK2(a0);
        if (rb + 1 < NN) *reinterpret_cast<uint2*>(yp + (size_t)(rb+1) * 16 + cp0) = PACK2(a1);
        if (rb + 2 < NN) *reinterpret_cast<uint2*>(yp + (size_t)(rb+2) * 16 + cp0) = PACK2(a2);
        if (rb + 3 < NN) *reinterpret_cast<uint2*>(yp + (size_t)(rb+3) * 16 + cp0) = PACK2(a3);
    } else {
        int cc  = c0 - DIM;
        int cp0 = cc >> 1;
        float4 bi = *reinterpret_cast<const float4*>(b_rel + cc);
        a0.x += bi.x; a0.y += bi.y; a0.z += bi.z; a0.w += bi.w;
        a1.x += bi.x; a1.y += bi.y; a1.z += bi.z; a1.w += bi.w;
        a2.x += bi.x; a2.y += bi.y; a2.z += bi.z; a2.w += bi.w;
        a3.x += bi.x; a3.y += bi.y; a3.z += bi.z; a3.w += bi.w;
        if (rb + 0 < NN) *reinterpret_cast<uint2*>(rootp + (size_t)(rb+0) * 16 + cp0) = PACK2(a0);
        if (rb + 1 < NN) *reinterpret_cast<uint2*>(rootp + (size_t)(rb+1) * 16 + cp0) = PACK2(a1);
        if (rb + 2 < NN) *reinterpret_cast<uint2*>(rootp + (size_t)(rb+2) * 16 + cp0) = PACK2(a2);
        if (rb + 3 < NN) *reinterpret_cast<uint2*>(rootp + (size_t)(rb+3) * 16 + cp0) = PACK2(a3);
    }
#undef PACK2
}

// ---------- k2: column prefix over the HB block rows -> colsum ----------
__global__ __launch_bounds__(256) void colscan(
    int* __restrict__ H, int* __restrict__ colsum)
{
    int b = blockIdx.x * 256 + threadIdx.x;
    if (b >= NB) return;
    int run = 0;
#pragma unroll 8
    for (int blk = 0; blk < HB; ++blk) {
        int v = H[blk * NB + b];   // coalesced across threads
        H[blk * NB + b] = run;
        run += v;
    }
    colsum[b] = run;
}

// ---------- k3: partition (LDS scan of colsum; block 0 exports boff) ----------
__global__ __launch_bounds__(256) void partition_kernel(
    const int* __restrict__ ei, const float* __restrict__ ew,
    const int* __restrict__ H, const int* __restrict__ colsum,
    uint2* __restrict__ part, int* __restrict__ boff)
{
    __shared__ int s_scan[256];
    __shared__ int s_boff[NB + 1];
    __shared__ int cur[NB];
    int t = threadIdx.x;
    {
        int v[4]; int sum = 0;
#pragma unroll
        for (int j = 0; j < 4; ++j) {
            int idx = t * 4 + j;
            v[j] = (idx < NB) ? colsum[idx] : 0;
            sum += v[j];
        }
        s_scan[t] = sum;
        __syncthreads();
        for (int o = 1; o < 256; o <<= 1) {
            int u = (t >= o) ? s_scan[t - o] : 0;
            __syncthreads();
            s_scan[t] += u;
            __syncthreads();
        }
        int b2 = s_scan[t] - sum;
#pragma unroll
        for (int j = 0; j < 4; ++j) {
            int idx = t * 4 + j;
            if (idx < NB) { s_boff[idx] = b2; b2 += v[j]; }
        }
        if (t == 0) s_boff[NB] = NE;
        __syncthreads();
    }
    if (blockIdx.x == 0)
        for (int i = t; i <= NB; i += 256) boff[i] = s_boff[i];

    for (int i = t; i < NB; i += 256)
        cur[i] = s_boff[i] + H[blockIdx.x * NB + i];
    __syncthreads();
    int base = blockIdx.x * CHUNK_E;
    int end  = min(base + CHUNK_E, NE);
    for (int e = base + t; e < end; e += 256) {
        int s = ei[e], d = ei[NE + e];
        float w = ew[e];
        int b = d >> 6;
        int pos = atomicAdd(&cur[b], 1);   // LDS atomic, block-local
        part[pos] = make_uint2((unsigned)s | ((unsigned)(d & 63) << 16),
                               __float_as_uint(w));
    }
}

// ---------- k4: fused bucket sort (LDS csr) + node aggregate + pool ----------
__global__ __launch_bounds__(256) void bucketagg_kernel(
    const uint2* __restrict__ ypq, const uint2* __restrict__ rootq,
    const uint2* __restrict__ part, const int* __restrict__ boff,
    const int* __restrict__ batch, float* __restrict__ pooled)
{
    __shared__ unsigned csr_lds[CAP];   // 8 KB
    __shared__ int cnt[BK];
    __shared__ int cur[BK];
    __shared__ int off[BK + 1];
    int b = blockIdx.x, t = threadIdx.x;
    int s0 = boff[b], s1 = boff[b + 1], m = s1 - s0;

    // sort phase: per-node counting sort of the bucket slice into LDS
    if (t < BK) cnt[t] = 0;
    __syncthreads();
    for (int i = t; i < m; i += 256)
        atomicAdd(&cnt[part[s0 + i].x >> 16], 1);
    __syncthreads();
    if (t < BK) {
        int v = cnt[t];
        int inc = v;
#pragma unroll
        for (int o = 1; o < BK; o <<= 1) {
            int u = __shfl_up(inc, o, 64);
            if (t >= o) inc += u;
        }
        off[t] = inc - v;
        cur[t] = inc - v;
        if (t == BK - 1) off[BK] = inc;
    }
    __syncthreads();
    for (int i = t; i < m; i += 256) {
        uint2 pk = part[s0 + i];
        int nl = pk.x >> 16;
        int pos = atomicAdd(&cur[nl], 1);
        csr_lds[pos] = (pk.x & 0xFFFFu) | (rne16(__uint_as_float(pk.y)) << 16);
    }
    __syncthreads();

    // agg phase: wave w handles nodes [w*16, w*16+16); 8 slots x 8 lanes
    int w    = t >> 6;
    int lane = t & 63;
    int s    = lane >> 3;
    int j    = lane & 7;
    int rung = -1;
    float r0 = 0, r1 = 0, r2 = 0, r3 = 0;
#pragma unroll 1
    for (int i = 0; i < 16; ++i) {
        int nl = w * 16 + i;
        int n  = b * BK + nl;
        if (n >= NN) break;
        int e0 = off[nl], e1 = off[nl + 1];
        float v0 = 0, v1 = 0, v2 = 0, v3 = 0;
        int e = e0 + s;
        for (; e + 8 < e1; e += 16) {
            unsigned c0 = csr_lds[e], c1 = csr_lds[e + 8];
            uint2 p0 = ypq[(c0 & 0xFFFFu) * 8 + j];
            uint2 p1 = ypq[(c1 & 0xFFFFu) * 8 + j];
            float w0 = UIF(c0 & 0xFFFF0000u), w1 = UIF(c1 & 0xFFFF0000u);
            v0 = fmaf(w0, blo(p0.x), v0); v1 = fmaf(w0, bhi(p0.x), v1);
            v2 = fmaf(w0, blo(p0.y), v2); v3 = fmaf(w0, bhi(p0.y), v3);
            v0 = fmaf(w1, blo(p1.x), v0); v1 = fmaf(w1, bhi(p1.x), v1);
            v2 = fmaf(w1, blo(p1.y), v2); v3 = fmaf(w1, bhi(p1.y), v3);
        }
        for (; e < e1; e += 8) {
            unsigned cu = csr_lds[e];
            uint2 p = ypq[(cu & 0xFFFFu) * 8 + j];
            float ww = UIF(cu & 0xFFFF0000u);
            v0 = fmaf(ww, blo(p.x), v0); v1 = fmaf(ww, bhi(p.x), v1);
            v2 = fmaf(ww, blo(p.y), v2); v3 = fmaf(ww, bhi(p.y), v3);
        }
        v0 += __shfl_xor(v0, 8, 64); v0 += __shfl_xor(v0, 16, 64); v0 += __shfl_xor(v0, 32, 64);
        v1 += __shfl_xor(v1, 8, 64); v1 += __shfl_xor(v1, 16, 64); v1 += __shfl_xor(v1, 32, 64);
        v2 += __shfl_xor(v2, 8, 64); v2 += __shfl_xor(v2, 16, 64); v2 += __shfl_xor(v2, 32, 64);
        v3 += __shfl_xor(v3, 8, 64); v3 += __shfl_xor(v3, 16, 64); v3 += __shfl_xor(v3, 32, 64);

        if (s == 0) {
            uint2 rr = rootq[(size_t)n * 8 + j];
            float o0 = fmaxf(v0 + blo(rr.x), 0.0f);
            float o1 = fmaxf(v1 + bhi(rr.x), 0.0f);
            float o2 = fmaxf(v2 + blo(rr.y), 0.0f);
            float o3 = fmaxf(v3 + bhi(rr.y), 0.0f);
            int g = batch[n];
            if (g != rung) {
                if (rung >= 0) {
                    atomicAdd(&pooled[rung * DIM + 4 * j + 0], r0);
                    atomicAdd(&pooled[rung * DIM + 4 * j + 1], r1);
                    atomicAdd(&pooled[rung * DIM + 4 * j + 2], r2);
                    atomicAdd(&pooled[rung * DIM + 4 * j + 3], r3);
                }
                rung = g; r0 = o0; r1 = o1; r2 = o2; r3 = o3;
            } else {
                r0 += o0; r1 += o1; r2 += o2; r3 += o3;
            }
        }
    }
    if (s == 0 && rung >= 0) {
        atomicAdd(&pooled[rung * DIM + 4 * j + 0], r0);
        atomicAdd(&pooled[rung * DIM + 4 * j + 1], r1);
        atomicAdd(&pooled[rung * DIM + 4 * j + 2], r2);
        atomicAdd(&pooled[rung * DIM + 4 * j + 3], r3);
    }
}

// ---------- k5: MLP head + log_softmax ----------
__global__ __launch_bounds__(512) void head_kernel(
    const float* __restrict__ pooled, const float* __restrict__ w_fc1,
    const float* __restrict__ b_fc1, const float* __restrict__ w_fc2,
    const float* __restrict__ b_fc2, float* __restrict__ out)
{
    __shared__ float s_fc1[DIM * DIM];
    __shared__ float s_b1[DIM];
    __shared__ float s_fc2[DIM * 2];
    __shared__ float s_b2[2];
    int tid = threadIdx.x;
    s_fc1[tid]       = w_fc1[tid];
    s_fc1[tid + 512] = w_fc1[tid + 512];
    if (tid < DIM * 2) s_fc2[tid] = w_fc2[tid];
    if (tid < DIM)     s_b1[tid]  = b_fc1[tid];
    if (tid < 2)       s_b2[tid]  = b_fc2[tid];
    __syncthreads();

    int g = tid;
    if (g >= NG) return;
    const float* p = pooled + g * DIM;
    float h2[DIM];
#pragma unroll
    for (int c = 0; c < DIM; ++c) {
        float a = s_b1[c];
#pragma unroll
        for (int k = 0; k < DIM; ++k)
            a = fmaf(p[k], s_fc1[k * DIM + c], a);
        h2[c] = a > 0.0f ? a : 0.0f;
    }
    float l0 = s_b2[0], l1 = s_b2[1];
#pragma unroll
    for (int c = 0; c < DIM; ++c) {
        l0 = fmaf(h2[c], s_fc2[c * 2 + 0], l0);
        l1 = fmaf(h2[c], s_fc2[c * 2 + 1], l1);
    }
    float m   = fmaxf(l0, l1);
    float lse = m + logf(expf(l0 - m) + expf(l1 - m));
    out[g * 2 + 0] = l0 - lse;
    out[g * 2 + 1] = l1 - lse;
}

extern "C" void kernel_launch(void* const* d_in, const int* in_sizes, int n_in,
                              void* d_out, int out_size, void* d_ws, size_t ws_size,
                              hipStream_t stream) {
    const float* x      = (const float*)d_in[0];
    const float* ew     = (const float*)d_in[1];
    const float* w_rel  = (const float*)d_in[2];
    const float* b_rel  = (const float*)d_in[3];
    const float* w_root = (const float*)d_in[4];
    const float* w_fc1  = (const float*)d_in[5];
    const float* b_fc1  = (const float*)d_in[6];
    const float* w_fc2  = (const float*)d_in[7];
    const float* b_fc2  = (const float*)d_in[8];
    const int*   ei     = (const int*)d_in[9];
    const int*   batch  = (const int*)d_in[10];
    float* out = (float*)d_out;

    char* ws = (char*)d_ws;
    unsigned* yp    = (unsigned*)ws;                           // 3.2 MB (bf16x2)
    unsigned* rootp = yp + (size_t)NN * 16;                    // 3.2 MB (bf16x2)
    uint2* part     = (uint2*)(rootp + (size_t)NN * 16);       // 6.4 MB
    int*   H        = (int*)(part + NE);                       // HB*NB = 800 KB
    int*   colsum   = H + (size_t)HB * NB;                     // NB
    int*   boff     = colsum + NB;                             // NB+1
    float* pooled   = (float*)(boff + NB + 2);                 // 64 KB

    projhist_kernel<<<NB + HB, 256, 0, stream>>>(x, w_rel, w_root, b_rel,
                                                 yp, rootp, ei, H, pooled);
    colscan<<<(NB + 255) / 256, 256, 0, stream>>>(H, colsum);
    partition_kernel<<<HB, 256, 0, stream>>>(ei, ew, H, colsum, part, boff);
    bucketagg_kernel<<<NB, 256, 0, stream>>>((const uint2*)yp, (const uint2*)rootp,
                                             part, boff, batch, pooled);
    head_kernel<<<1, 512, 0, stream>>>(pooled, w_fc1, b_fc1, w_fc2, b_fc2, out);
}